// Round 14
// baseline (255.259 us; speedup 1.0000x reference)
//
#include <hip/hip_runtime.h>
#include <hip/hip_bf16.h>

typedef short s16;
typedef __attribute__((ext_vector_type(8))) short bf16x8;  // 8 bf16 = 4 VGPR (MFMA A/B frag)
typedef __attribute__((ext_vector_type(4))) float f32x4;   // MFMA C/D frag

// ---------------- helpers ----------------
__device__ __forceinline__ s16 f2bf(float f) {
  unsigned u = __builtin_bit_cast(unsigned, f);
  unsigned r = (u + 0x7FFFu + ((u >> 16) & 1u)) >> 16;
  return (s16)r;
}

__device__ __forceinline__ float hsig(float x) {
  return fminf(fmaxf(0.2f * x + 0.5f, 0.0f), 1.0f);
}

#define PXS 66
#define ROWSZ (PXS * 64)             // 4224 elements per tile row
#define ASZ4 (4 * ROWSZ)             // 4-row tile (layer-1 / probe)
#define ASZ6 (6 * ROWSZ)             // 6-row tile (layer-0)

// ---------------- prep kernel ----------------
// Lane-direct weight layout: wq[stage u = tap*2+k][j][g][lane][8]
// lane = l4*16+l15, oc = j*64+g*16+l15, ic = k*32+l4*8+e.
__global__ void wprep_kernel(const float* __restrict__ rk0, const float* __restrict__ k1,
                             const float* __restrict__ rk1, const float* __restrict__ k0,
                             s16* __restrict__ w0q, s16* __restrict__ w1q,
                             s16* __restrict__ w2q, s16* __restrict__ k0t) {
  int idx = blockIdx.x * 256 + threadIdx.x;
  const int n1 = 18 * 8192;  // 147456
  if (idx < 3 * n1) {
    int which = idx / n1;
    int i = idx - which * n1;
    int e    = i & 7;
    int lane = (i >> 3) & 63;
    int g    = (i >> 9) & 3;
    int j    = (i >> 11) & 3;
    int k    = (i >> 13) & 1;
    int tap  = i >> 14;
    int l15 = lane & 15, l4 = lane >> 4;
    int ic = k * 32 + l4 * 8 + e;
    int oc = j * 64 + g * 16 + l15;
    const float* src = (which == 0) ? rk0 : (which == 1) ? k1 : rk1;
    s16* dst = (which == 0) ? w0q : (which == 1) ? w1q : w2q;
    dst[i] = f2bf(src[(tap * 64 + ic) * 256 + oc]);
  } else if (idx < 3 * n1 + 8192) {
    int r = idx - 3 * n1;
    int kk = r & 31;
    int oc = r >> 5;
    k0t[r] = (kk < 9) ? f2bf(k0[kk * 256 + oc]) : (s16)0;
  }
}

// ---------------- staging helpers ----------------
template <bool F32>
__device__ __forceinline__ bf16x8 load_conv8(const void* src, long off) {
  if constexpr (F32) {
    const float* p = (const float*)src + off;
    float4 v0 = *reinterpret_cast<const float4*>(p);
    float4 v1 = *reinterpret_cast<const float4*>(p + 4);
    bf16x8 r;
    r[0] = f2bf(v0.x); r[1] = f2bf(v0.y); r[2] = f2bf(v0.z); r[3] = f2bf(v0.w);
    r[4] = f2bf(v1.x); r[5] = f2bf(v1.y); r[6] = f2bf(v1.z); r[7] = f2bf(v1.w);
    return r;
  } else {
    return *reinterpret_cast<const bf16x8*>((const s16*)src + off);
  }
}

// 4-row tile, 512 threads
template <bool F32>
__device__ __forceinline__ void stage4(s16* a_lds, const void* src, int b, int y0, int tid) {
  #pragma unroll
  for (int i = 0; i < 4; ++i) {
    int c   = tid + i * 512;        // 0..2047 16B-chunks
    int row = c >> 9;               // 0..3
    int px  = (c >> 3) & 63;
    int cb  = c & 7;
    int y   = y0 - 1 + row;
    int xp  = px + 1;
    bf16x8 v = {};
    if ((unsigned)y < 64u)
      v = load_conv8<F32>(src, ((long)(b * 64 + y) * 64 + px) * 64 + cb * 8);
    *reinterpret_cast<bf16x8*>(a_lds + (row * PXS + xp) * 64 + ((cb ^ (xp & 7)) * 8)) = v;
  }
  if (tid < 64) {  // zero x-border columns (xp = 0, 65)
    int row = tid >> 4;
    int xp  = ((tid >> 3) & 1) ? 65 : 0;
    int cb  = tid & 7;
    bf16x8 z = {};
    *reinterpret_cast<bf16x8*>(a_lds + (row * PXS + xp) * 64 + cb * 8) = z;
  }
}

// 6-row tile, 1024 threads
template <bool F32>
__device__ __forceinline__ void stage6(s16* a_lds, const void* src, int b, int y0, int tid) {
  #pragma unroll
  for (int i = 0; i < 3; ++i) {
    int c   = tid + i * 1024;       // 0..3071 16B-chunks
    int row = c >> 9;               // 0..5
    int px  = (c >> 3) & 63;
    int cb  = c & 7;
    int y   = y0 - 1 + row;
    int xp  = px + 1;
    bf16x8 v = {};
    if ((unsigned)y < 64u)
      v = load_conv8<F32>(src, ((long)(b * 64 + y) * 64 + px) * 64 + cb * 8);
    *reinterpret_cast<bf16x8*>(a_lds + (row * PXS + xp) * 64 + ((cb ^ (xp & 7)) * 8)) = v;
  }
  if (tid < 96) {
    int row = tid >> 4;
    int xp  = ((tid >> 3) & 1) ? 65 : 0;
    int cb  = tid & 7;
    bf16x8 z = {};
    *reinterpret_cast<bf16x8*>(a_lds + (row * PXS + xp) * 64 + cb * 8) = z;
  }
}

// ---------------- LAYER 0 cell (R13 structure: 1024 thr, M=256, W-LDS counted) ----------------
__global__ __launch_bounds__(1024, 4) void cell0_kernel(
    const float* __restrict__ h0,   // [B,64,64,64] fp32
    const s16* __restrict__ w0,     // wq layout [18][8192]
    const float* __restrict__ xin,  // [B,64,64] fp32
    const s16* __restrict__ k0t,    // [256][32]
    const float* __restrict__ bias,
    const float* __restrict__ c_old,
    float* __restrict__ h_out,
    float* __restrict__ c_out,
    s16* __restrict__ hb_out)
{
  __shared__ __align__(16) s16 a_lds[ASZ6];
  __shared__ __align__(16) s16 w_lds[2][8192];
  __shared__ float x_lds[384];

  const int tid = threadIdx.x;
  const int b  = blockIdx.x >> 4;
  const int y0 = (blockIdx.x & 15) << 2;

  const int wave = tid >> 6;
  const int lane = tid & 63;
  const int g    = wave & 3;
  const int mh   = wave >> 2;   // 0..3: output row
  const int l15  = lane & 15;
  const int l4   = lane >> 4;

  constexpr int NST = 18;

  auto issueW = [&](int u) {
    int v = (u >= NST) ? u - NST : u;
    const s16* wt = w0 + v * 8192;
    char* base = (char*)(&w_lds[0][0]) + (v & 1) * 16384 + (tid >> 6) * 1024;
    __builtin_amdgcn_global_load_lds(
        (const __attribute__((address_space(1))) void*)(wt + tid * 8),
        (__attribute__((address_space(3))) void*)base, 16, 0, 0);
  };
  auto readWf = [&](bf16x8 (&wf)[4], int slot) {
    const s16* wb = &w_lds[slot][0] + g * 512 + lane * 8;
    #pragma unroll
    for (int j = 0; j < 4; ++j)
      wf[j] = *reinterpret_cast<const bf16x8*>(wb + j * 2048);
  };

  f32x4 acc[4][4] = {};

  auto doStage = [&](const bf16x8 (&wf)[4], int u) {
    int tap = u >> 1, kk = u & 1;
    int dy = tap / 3, dx = tap - dy * 3;
    const char* sb = (const char*)a_lds + (mh + dy) * (ROWSZ * 2);
    bf16x8 af[4];
    #pragma unroll
    for (int m = 0; m < 4; ++m) {
      int xq   = m * 16 + l15 + dx;
      int boff = xq * 128 + ((((kk << 2) | l4) ^ (xq & 7)) << 4);
      af[m] = *reinterpret_cast<const bf16x8*>(sb + boff);
    }
    __builtin_amdgcn_s_setprio(1);
    #pragma unroll
    for (int m = 0; m < 4; ++m) {
      #pragma unroll
      for (int j = 0; j < 4; ++j)
        acc[m][j] = __builtin_amdgcn_mfma_f32_16x16x32_bf16(af[m], wf[j], acc[m][j], 0, 0, 0);
    }
    __builtin_amdgcn_s_setprio(0);
  };

  issueW(0);
  issueW(1);
  stage6<true>(a_lds, h0, b, y0, tid);
  if (tid < 384) {
    int row = tid >> 6, px = tid & 63;
    int y = y0 - 1 + row;
    x_lds[tid] = ((unsigned)y < 64u) ? xin[(b * 64 + y) * 64 + px] : 0.0f;
  }
  __syncthreads();

  // x-conv as one zero-padded K=32 MFMA step
  {
    bf16x8 bx[4];
    #pragma unroll
    for (int j = 0; j < 4; ++j) {
      int oc = j * 64 + g * 16 + l15;
      bx[j] = *reinterpret_cast<const bf16x8*>(k0t + oc * 32 + l4 * 8);
    }
    #pragma unroll
    for (int m = 0; m < 4; ++m) {
      int px = m * 16 + l15;
      bf16x8 ax = {};
      #pragma unroll
      for (int e = 0; e < 8; ++e) {
        int t = l4 * 8 + e;
        if (t < 9) {
          int dyt = t / 3, dxt = t - dyt * 3;
          int xx = px + dxt - 1;
          float xv = ((unsigned)xx < 64u) ? x_lds[(mh + dyt) * 64 + xx] : 0.0f;
          ax[e] = f2bf(xv);
        }
      }
      #pragma unroll
      for (int j = 0; j < 4; ++j)
        acc[m][j] = __builtin_amdgcn_mfma_f32_16x16x32_bf16(ax, bx[j], acc[m][j], 0, 0, 0);
    }
  }

  bf16x8 wfA[4], wfB[4];
  readWf(wfA, 0);
  #pragma unroll
  for (int u = 0; u < NST; u += 2) {
    __builtin_amdgcn_s_barrier();
    issueW(u + 2);
    asm volatile("s_waitcnt vmcnt(1)" ::: "memory");
    __builtin_amdgcn_s_barrier();
    readWf(wfB, (u + 1) & 1);
    doStage(wfA, u);
    __builtin_amdgcn_s_barrier();
    issueW(u + 3);
    asm volatile("s_waitcnt vmcnt(1)" ::: "memory");
    __builtin_amdgcn_s_barrier();
    readWf(wfA, u & 1);
    doStage(wfB, u + 1);
  }

  float bi[4];
  #pragma unroll
  for (int j = 0; j < 4; ++j) bi[j] = bias[j * 64 + g * 16 + l15];
  const int pix_base = b * 4096 + y0 * 64;
  const int f = g * 16 + l15;
  #pragma unroll
  for (int m = 0; m < 4; ++m) {
    #pragma unroll
    for (int r = 0; r < 4; ++r) {
      int pl = mh * 64 + m * 16 + l4 * 4 + r;
      int off = (pix_base + pl) * 64 + f;
      float zi = acc[m][0][r] + bi[0];
      float zf = acc[m][1][r] + bi[1];
      float zc = acc[m][2][r] + bi[2];
      float zo = acc[m][3][r] + bi[3];
      float ig = hsig(zi), fg = hsig(zf), og = hsig(zo);
      float cn = fg * c_old[off] + ig * tanhf(zc);
      float hn = og * tanhf(cn);
      c_out[off] = cn;
      h_out[off] = hn;
      hb_out[off] = f2bf(hn);
    }
  }
}

// ---------------- LAYER 1 cell (R6 structure: 512 thr, M=128, barrier-free W->reg) ----------------
__global__ __launch_bounds__(512, 4) void cell1_kernel(
    const s16* __restrict__ src0,   // h0nb bf16
    const float* __restrict__ src1, // h1 fp32
    const s16* __restrict__ w0,     // k1 wq
    const s16* __restrict__ w1,     // rk1 wq
    const float* __restrict__ bias,
    const float* __restrict__ c_old,
    float* __restrict__ h_out,
    float* __restrict__ c_out)
{
  __shared__ __align__(16) s16 a_lds[2 * ASZ4];

  const int tid = threadIdx.x;
  const int b  = blockIdx.x >> 5;
  const int y0 = (blockIdx.x & 31) << 1;

  stage4<false>(a_lds, src0, b, y0, tid);
  stage4<true>(a_lds + ASZ4, src1, b, y0, tid);
  __syncthreads();   // the only block-wide sync

  const int wave = tid >> 6;
  const int lane = tid & 63;
  const int g    = wave & 3;
  const int mh   = wave >> 2;
  const int l15  = lane & 15;
  const int l4   = lane >> 4;

  f32x4 acc[4][4] = {};

  const int wl_off = g * 512 + lane * 8;
  auto loadW = [&](bf16x8 (&wf)[4], int u) {
    int si = (u >= 18) ? 1 : 0;
    const s16* wp = (si ? w1 : w0) + (u - 18 * si) * 8192 + wl_off;
    #pragma unroll
    for (int j = 0; j < 4; ++j)
      wf[j] = *reinterpret_cast<const bf16x8*>(wp + j * 2048);
  };
  auto doStage = [&](const bf16x8 (&wf)[4], int u) {
    int si = (u >= 18) ? 1 : 0;
    int uu = u - 18 * si;
    int tap = uu >> 1, kk = uu & 1;
    int dy = tap / 3, dx = tap - dy * 3;
    const char* lb = (const char*)a_lds + (si * ASZ4 + (mh + dy) * ROWSZ) * 2;
    #pragma unroll
    for (int m = 0; m < 4; ++m) {
      int xq   = m * 16 + l15 + dx;
      int boff = xq * 128 + (((kk << 6) | (l4 << 4)) ^ ((xq & 7) << 4));
      bf16x8 a = *reinterpret_cast<const bf16x8*>(lb + boff);
      #pragma unroll
      for (int j = 0; j < 4; ++j)
        acc[m][j] = __builtin_amdgcn_mfma_f32_16x16x32_bf16(a, wf[j], acc[m][j], 0, 0, 0);
    }
  };

  bf16x8 wfA[4], wfB[4];
  loadW(wfA, 0);
  loadW(wfB, 1);
  #pragma unroll
  for (int u = 0; u < 36; u += 2) {
    doStage(wfA, u);
    if (u + 2 < 36) loadW(wfA, u + 2);
    doStage(wfB, u + 1);
    if (u + 3 < 36) loadW(wfB, u + 3);
  }

  float bi[4];
  #pragma unroll
  for (int j = 0; j < 4; ++j) bi[j] = bias[j * 64 + g * 16 + l15];
  const int pix_base = b * 4096 + y0 * 64;
  const int f = g * 16 + l15;
  #pragma unroll
  for (int m = 0; m < 4; ++m) {
    #pragma unroll
    for (int r = 0; r < 4; ++r) {
      int pl = mh * 64 + m * 16 + l4 * 4 + r;
      int off = (pix_base + pl) * 64 + f;
      float zi = acc[m][0][r] + bi[0];
      float zf = acc[m][1][r] + bi[1];
      float zc = acc[m][2][r] + bi[2];
      float zo = acc[m][3][r] + bi[3];
      float ig = hsig(zi), fg = hsig(zf), og = hsig(zo);
      float cn = fg * c_old[off] + ig * tanhf(zc);
      float hn = og * tanhf(cn);
      c_out[off] = cn;
      h_out[off] = hn;
    }
  }
}

// ---------------- ABLATION PROBE noA: cell1 clone, A-ds_reads frozen ----------------
// W stream (per-stage global loads) INTACT; A frags loaded once at stage 0 and
// reused. Complement of R11's probe (which froze W). Readout: W-stream-only cost.
__global__ __launch_bounds__(512, 4) void probe_noA(
    const s16* __restrict__ src0, const s16* __restrict__ src1,
    const s16* __restrict__ w0, const s16* __restrict__ w1,
    float* __restrict__ sink)
{
  __shared__ __align__(16) s16 a_lds[2 * ASZ4];
  const int tid = threadIdx.x;
  const int b  = blockIdx.x >> 5;
  const int y0 = (blockIdx.x & 31) << 1;

  stage4<false>(a_lds, src0, b, y0, tid);
  stage4<false>(a_lds + ASZ4, src1, b, y0, tid);
  __syncthreads();

  const int wave = tid >> 6;
  const int lane = tid & 63;
  const int g    = wave & 3;
  const int mh   = wave >> 2;
  const int l15  = lane & 15;
  const int l4   = lane >> 4;

  f32x4 acc[4][4] = {};

  // frozen A frags (stage 0 pattern)
  bf16x8 af[4];
  {
    const char* lb = (const char*)a_lds + (mh * ROWSZ) * 2;
    #pragma unroll
    for (int m = 0; m < 4; ++m) {
      int xq   = m * 16 + l15;
      int boff = xq * 128 + ((l4 << 4) ^ ((xq & 7) << 4));
      af[m] = *reinterpret_cast<const bf16x8*>(lb + boff);
    }
  }

  const int wl_off = g * 512 + lane * 8;
  auto loadW = [&](bf16x8 (&wf)[4], int u) {
    int si = (u >= 18) ? 1 : 0;
    const s16* wp = (si ? w1 : w0) + (u - 18 * si) * 8192 + wl_off;
    #pragma unroll
    for (int j = 0; j < 4; ++j)
      wf[j] = *reinterpret_cast<const bf16x8*>(wp + j * 2048);
  };
  auto doStage = [&](const bf16x8 (&wf)[4]) {
    #pragma unroll
    for (int m = 0; m < 4; ++m) {
      #pragma unroll
      for (int j = 0; j < 4; ++j)
        acc[m][j] = __builtin_amdgcn_mfma_f32_16x16x32_bf16(af[m], wf[j], acc[m][j], 0, 0, 0);
    }
  };

  bf16x8 wfA[4], wfB[4];
  loadW(wfA, 0);
  loadW(wfB, 1);
  #pragma unroll
  for (int u = 0; u < 36; u += 2) {
    doStage(wfA);
    if (u + 2 < 36) loadW(wfA, u + 2);
    doStage(wfB);
    if (u + 3 < 36) loadW(wfB, u + 3);
  }

  float s = 0.0f;
  #pragma unroll
  for (int m = 0; m < 4; ++m)
    #pragma unroll
    for (int j = 0; j < 4; ++j)
      #pragma unroll
      for (int r = 0; r < 4; ++r) s += acc[m][j][r];
  if (lane == 0) sink[blockIdx.x * 8 + wave] = s;
}

// ---------------- 1x1 conv head ----------------
__global__ void frames_kernel(const float* __restrict__ h, const float* __restrict__ cw,
                              const float* __restrict__ cbp, float* __restrict__ out) {
  int tid = blockIdx.x * 256 + threadIdx.x;
  int p  = tid >> 2;
  int fc = (tid & 3) * 16;
  const float4* hp = reinterpret_cast<const float4*>(h + p * 64 + fc);
  const float4* wp = reinterpret_cast<const float4*>(cw + fc);
  float s = 0.0f;
  #pragma unroll
  for (int i = 0; i < 4; ++i) {
    float4 v = hp[i];
    float4 w = wp[i];
    s += v.x * w.x + v.y * w.y + v.z * w.z + v.w * w.w;
  }
  s += __shfl_xor(s, 1);
  s += __shfl_xor(s, 2);
  if ((tid & 3) == 0) out[p] = s + cbp[0];
}

// ---------------- launch ----------------
extern "C" void kernel_launch(void* const* d_in, const int* in_sizes, int n_in,
                              void* d_out, int out_size, void* d_ws, size_t ws_size,
                              hipStream_t stream) {
  const float* x   = (const float*)d_in[0];
  const float* h0  = (const float*)d_in[1];
  const float* c0  = (const float*)d_in[2];
  const float* h1  = (const float*)d_in[3];
  const float* c1  = (const float*)d_in[4];
  const float* k0  = (const float*)d_in[5];
  const float* rk0 = (const float*)d_in[6];
  const float* b0  = (const float*)d_in[7];
  const float* k1  = (const float*)d_in[8];
  const float* rk1 = (const float*)d_in[9];
  const float* b1  = (const float*)d_in[10];
  const float* cw  = (const float*)d_in[11];
  const float* cbp = (const float*)d_in[12];

  float* out    = (float*)d_out;
  float* frames = out;                       // [32,64,64,1]
  float* h0n    = out + 131072;              // [32,64,64,64]
  float* c0n    = out + 131072 + 8388608;
  float* h1n    = out + 131072 + 2 * 8388608;
  float* c1n    = out + 131072 + 3 * 8388608;

  char* ws = (char*)d_ws;
  const size_t SZ_H = 16777216;  // bytes per bf16 [32,64,64,64] buffer
  s16* h0nb = (s16*)(ws + 0 * SZ_H);
  s16* w0q  = (s16*)(ws + 1 * SZ_H);                 // rk0 shuffled
  s16* w1q  = (s16*)(ws + 1 * SZ_H + 1 * 294912);    // k1 shuffled
  s16* w2q  = (s16*)(ws + 1 * SZ_H + 2 * 294912);    // rk1 shuffled
  s16* k0t  = (s16*)(ws + 1 * SZ_H + 3 * 294912);    // k0 padded [256][32]
  float* sink = (float*)(ws + 1 * SZ_H + 4 * 294912);

  // prep (single launch)
  wprep_kernel<<<1760, 256, 0, stream>>>(rk0, k1, rk1, k0, w0q, w1q, w2q, k0t);

  // layer 0 (R13 structure, measured best L0)
  cell0_kernel<<<512, 1024, 0, stream>>>(
      h0, w0q, x, k0t, b0, c0, h0n, c0n, h0nb);

  // layer 1 (R6 structure, measured best L1)
  cell1_kernel<<<1024, 512, 0, stream>>>(
      h0nb, h1, w1q, w2q, b1, c1, h1n, c1n);

  // head
  frames_kernel<<<2048, 256, 0, stream>>>(h1n, cw, cbp, frames);

  // ABLATION PROBE (diagnostic): W stream intact, A reads frozen.
  probe_noA<<<1024, 512, 0, stream>>>(h0nb, h0nb, w1q, w2q, sink);
}

// Round 15
// 185.523 us; speedup vs baseline: 1.3759x; 1.3759x over previous
//
#include <hip/hip_runtime.h>
#include <hip/hip_bf16.h>

typedef short s16;
typedef __attribute__((ext_vector_type(8))) short bf16x8;  // 8 bf16 = 4 VGPR (MFMA A/B frag)
typedef __attribute__((ext_vector_type(4))) float f32x4;   // MFMA C/D frag

// ---------------- helpers ----------------
__device__ __forceinline__ s16 f2bf(float f) {
  unsigned u = __builtin_bit_cast(unsigned, f);
  unsigned r = (u + 0x7FFFu + ((u >> 16) & 1u)) >> 16;
  return (s16)r;
}

__device__ __forceinline__ float hsig(float x) {
  return fminf(fmaxf(0.2f * x + 0.5f, 0.0f), 1.0f);
}

#define PXS 66
#define ROWSZ (PXS * 64)             // 4224 elements per tile row
#define ASZ6 (6 * ROWSZ)             // 6-row tile (25344 elems)

// ---------------- prep kernel ----------------
// Weight layout per half-tap stage slice (16 KB = 8192 elems):
//   wq[stage u = tap*2+k][j][g][lane][8]
// lane = l4*16+l15, oc = j*64+g*16+l15, ic = k*32+l4*8+e.
__global__ void wprep_kernel(const float* __restrict__ rk0, const float* __restrict__ k1,
                             const float* __restrict__ rk1, const float* __restrict__ k0,
                             s16* __restrict__ w0q, s16* __restrict__ w1q,
                             s16* __restrict__ w2q, s16* __restrict__ k0t) {
  int idx = blockIdx.x * 256 + threadIdx.x;
  const int n1 = 18 * 8192;  // 147456
  if (idx < 3 * n1) {
    int which = idx / n1;
    int i = idx - which * n1;
    int e    = i & 7;
    int lane = (i >> 3) & 63;
    int g    = (i >> 9) & 3;
    int j    = (i >> 11) & 3;
    int k    = (i >> 13) & 1;
    int tap  = i >> 14;
    int l15 = lane & 15, l4 = lane >> 4;
    int ic = k * 32 + l4 * 8 + e;
    int oc = j * 64 + g * 16 + l15;
    const float* src = (which == 0) ? rk0 : (which == 1) ? k1 : rk1;
    s16* dst = (which == 0) ? w0q : (which == 1) ? w1q : w2q;
    dst[i] = f2bf(src[(tap * 64 + ic) * 256 + oc]);
  } else if (idx < 3 * n1 + 8192) {
    int r = idx - 3 * n1;
    int kk = r & 31;
    int oc = r >> 5;
    k0t[r] = (kk < 9) ? f2bf(k0[kk * 256 + oc]) : (s16)0;
  }
}

// ---------------- staging ----------------
template <bool F32>
__device__ __forceinline__ bf16x8 load_conv8(const void* src, long off) {
  if constexpr (F32) {
    const float* p = (const float*)src + off;
    float4 v0 = *reinterpret_cast<const float4*>(p);
    float4 v1 = *reinterpret_cast<const float4*>(p + 4);
    bf16x8 r;
    r[0] = f2bf(v0.x); r[1] = f2bf(v0.y); r[2] = f2bf(v0.z); r[3] = f2bf(v0.w);
    r[4] = f2bf(v1.x); r[5] = f2bf(v1.y); r[6] = f2bf(v1.z); r[7] = f2bf(v1.w);
    return r;
  } else {
    return *reinterpret_cast<const bf16x8*>((const s16*)src + off);
  }
}

// 6-row tile, 1024 threads
template <bool F32>
__device__ __forceinline__ void stage6(s16* a_lds, const void* src, int b, int y0, int tid) {
  #pragma unroll
  for (int i = 0; i < 3; ++i) {
    int c   = tid + i * 1024;       // 0..3071 16B-chunks
    int row = c >> 9;               // 0..5
    int px  = (c >> 3) & 63;
    int cb  = c & 7;
    int y   = y0 - 1 + row;
    int xp  = px + 1;
    bf16x8 v = {};
    if ((unsigned)y < 64u)
      v = load_conv8<F32>(src, ((long)(b * 64 + y) * 64 + px) * 64 + cb * 8);
    *reinterpret_cast<bf16x8*>(a_lds + (row * PXS + xp) * 64 + ((cb ^ (xp & 7)) * 8)) = v;
  }
  if (tid < 96) {  // zero x-border columns (xp = 0, 65), rows 0..5
    int row = tid >> 4;
    int xp  = ((tid >> 3) & 1) ? 65 : 0;
    int cb  = tid & 7;
    bf16x8 z = {};
    *reinterpret_cast<bf16x8*>(a_lds + (row * PXS + xp) * 64 + cb * 8) = z;
  }
}

// ---------------- ConvLSTM cell kernel ----------------
// Block: 1024 threads = 16 waves, 1 block/CU (LDS 147 KB layer-1), 4 waves/SIMD.
// Tile: M=256 px (4 output rows), N=256. Wave (mh=wave>>2 : output row, g=wave&3
// : oc quarter); acc[4][4]=64 AGPR; all 4 gates of (px,f) lane-local.
// W pipeline (the R14 probes showed W+A stream INTERFERENCE is the wall):
// 3-slot LDS ring, issue distance 2, ONE barrier per stage:
//   vmcnt(1) [slice u landed - issued 2 stages ago] -> s_barrier [publish +
//   retire slot readers] -> sched_barrier -> issueW(u+2) into slot (u+2)%3
//   -> ds_read W frags (slot u%3) + A frags -> 16 MFMA (setprio).
// Safety: S=3 does not divide d+1=3?  write slot (u+2)%3, concurrent stragglers
// read slice u-1 -> issue is AFTER barrier so all waves are in stage u; readers
// of slot (u+2)%3 were at stage u-1, separated by this stage's barrier.
// grid: 512 blocks: b = blk>>4, y0 = (blk&15)*4.
template <int NSRC, bool XPATH, bool S0F32, bool S1F32>
__global__ __launch_bounds__(1024, 1) void cell_kernel(
    const void* __restrict__ src0,  // [B,64,64,64] bf16 or fp32
    const void* __restrict__ src1,  // [B,64,64,64] bf16 or fp32 (NSRC==2)
    const s16* __restrict__ w0,     // wq layout [18][8192] bf16
    const s16* __restrict__ w1,     // wq layout (NSRC==2)
    const float* __restrict__ xin,  // [B,64,64] fp32 (XPATH)
    const s16* __restrict__ k0t,    // [256][32] bf16 (XPATH)
    const float* __restrict__ bias, // [256]
    const float* __restrict__ c_old,// [B,64,64,64] fp32
    float* __restrict__ h_out,
    float* __restrict__ c_out,
    s16* __restrict__ hb_out)       // bf16 copy of h (nullable)
{
  __shared__ __align__(16) s16 a_lds[NSRC * ASZ6];  // 49.5 KB per source
  __shared__ __align__(16) s16 w_lds[3][8192];      // 3 x 16 KB W ring
  __shared__ float x_lds[XPATH ? 384 : 1];

  const int tid = threadIdx.x;
  const int b  = blockIdx.x >> 4;
  const int y0 = (blockIdx.x & 15) << 2;

  const int wave = tid >> 6;
  const int lane = tid & 63;
  const int g    = wave & 3;
  const int mh   = wave >> 2;   // 0..3: output row within the 4-row tile
  const int l15  = lane & 15;
  const int l4   = lane >> 4;

  constexpr int NST = NSRC * 18;   // 18 or 36 (both % 3 == 0)

  // ---- W slice issue: 1 x 16B global_load_lds per thread, slot v%3 ----
  auto issueW = [&](int u) {
    int v = (u >= NST) ? u - NST : u;   // wrap dummy; slot pattern preserved (NST%3==0)
    int si = (NSRC == 2 && v >= 18) ? 1 : 0;
    int vv = v - 18 * si;
    const s16* wt = (si ? w1 : w0) + vv * 8192;
    char* base = (char*)(&w_lds[0][0]) + (v % 3) * 16384 + (tid >> 6) * 1024;
    __builtin_amdgcn_global_load_lds(
        (const __attribute__((address_space(1))) void*)(wt + tid * 8),
        (__attribute__((address_space(3))) void*)base, 16, 0, 0);
  };

  auto readWf = [&](bf16x8 (&wf)[4], int slot) {
    const s16* wb = &w_lds[slot][0] + g * 512 + lane * 8;
    #pragma unroll
    for (int j = 0; j < 4; ++j)
      wf[j] = *reinterpret_cast<const bf16x8*>(wb + j * 2048);
  };

  f32x4 acc[4][4] = {};  // [m-frag][gate j] -- 64 regs (AGPR)

  auto doStage = [&](const bf16x8 (&wf)[4], int u) {  // u compile-time via unroll
    int si = (NSRC == 2 && u >= 18) ? 1 : 0;
    int uu = u - 18 * si;
    int tap = uu >> 1, kk = uu & 1;
    int dy = tap / 3, dx = tap - dy * 3;
    const char* sb = (const char*)a_lds + si * (ASZ6 * 2) + (mh + dy) * (ROWSZ * 2);
    bf16x8 af[4];
    #pragma unroll
    for (int m = 0; m < 4; ++m) {
      int xq   = m * 16 + l15 + dx;
      int boff = xq * 128 + ((((kk << 2) | l4) ^ (xq & 7)) << 4);
      af[m] = *reinterpret_cast<const bf16x8*>(sb + boff);
    }
    __builtin_amdgcn_s_setprio(1);
    #pragma unroll
    for (int m = 0; m < 4; ++m) {
      #pragma unroll
      for (int j = 0; j < 4; ++j)
        acc[m][j] = __builtin_amdgcn_mfma_f32_16x16x32_bf16(af[m], wf[j], acc[m][j], 0, 0, 0);
    }
    __builtin_amdgcn_s_setprio(0);
  };

  // ---- prologue: issue W slices 0,1; stage A ----
  issueW(0);
  issueW(1);
  stage6<S0F32>(a_lds, src0, b, y0, tid);
  if (NSRC == 2) stage6<S1F32>(a_lds + ASZ6, src1, b, y0, tid);
  if (XPATH) {
    if (tid < 384) {
      int row = tid >> 6, px = tid & 63;
      int y = y0 - 1 + row;
      x_lds[tid] = ((unsigned)y < 64u) ? xin[(b * 64 + y) * 64 + px] : 0.0f;
    }
  }
  __syncthreads();   // drains vmcnt+lgkm: A staged, W slices 0,1 landed

  // ---- x-conv as one zero-padded K=32 MFMA step (layer 0 only) ----
  if (XPATH) {
    bf16x8 bx[4];
    #pragma unroll
    for (int j = 0; j < 4; ++j) {
      int oc = j * 64 + g * 16 + l15;
      bx[j] = *reinterpret_cast<const bf16x8*>(k0t + oc * 32 + l4 * 8);
    }
    #pragma unroll
    for (int m = 0; m < 4; ++m) {
      int px = m * 16 + l15;
      bf16x8 ax = {};
      #pragma unroll
      for (int e = 0; e < 8; ++e) {
        int t = l4 * 8 + e;
        if (t < 9) {
          int dyt = t / 3, dxt = t - dyt * 3;
          int xx = px + dxt - 1;
          float xv = ((unsigned)xx < 64u) ? x_lds[(mh + dyt) * 64 + xx] : 0.0f;
          ax[e] = f2bf(xv);
        }
      }
      #pragma unroll
      for (int j = 0; j < 4; ++j)
        acc[m][j] = __builtin_amdgcn_mfma_f32_16x16x32_bf16(ax, bx[j], acc[m][j], 0, 0, 0);
    }
  }

  // ---- main K loop: one barrier/stage, counted vmcnt(1), 3-slot W ring ----
  bf16x8 wf[4];
  #pragma unroll
  for (int u = 0; u < NST; ++u) {
    asm volatile("s_waitcnt vmcnt(1)" ::: "memory");  // slice u landed (issued u-2)
    __builtin_amdgcn_s_barrier();                     // publish slice u; retire slot readers
    __builtin_amdgcn_sched_barrier(0);                // no hoisting across the barrier
    issueW(u + 2);                                    // slot (u+2)%3 (readers done @u-1)
    readWf(wf, u % 3);
    doStage(wf, u);
  }

  // ---- LSTM epilogue (lane-local gates) ----
  float bi[4];
  #pragma unroll
  for (int j = 0; j < 4; ++j) bi[j] = bias[j * 64 + g * 16 + l15];

  const int pix_base = b * 4096 + y0 * 64;
  const int f = g * 16 + l15;
  #pragma unroll
  for (int m = 0; m < 4; ++m) {
    #pragma unroll
    for (int r = 0; r < 4; ++r) {
      int pl = mh * 64 + m * 16 + l4 * 4 + r;
      int off = (pix_base + pl) * 64 + f;
      float zi = acc[m][0][r] + bi[0];
      float zf = acc[m][1][r] + bi[1];
      float zc = acc[m][2][r] + bi[2];
      float zo = acc[m][3][r] + bi[3];
      float ig = hsig(zi), fg = hsig(zf), og = hsig(zo);
      float cn = fg * c_old[off] + ig * tanhf(zc);
      float hn = og * tanhf(cn);
      c_out[off] = cn;
      h_out[off] = hn;
      if (hb_out) hb_out[off] = f2bf(hn);
    }
  }
}

// ---------------- 1x1 conv head ----------------
__global__ void frames_kernel(const float* __restrict__ h, const float* __restrict__ cw,
                              const float* __restrict__ cbp, float* __restrict__ out) {
  int tid = blockIdx.x * 256 + threadIdx.x;
  int p  = tid >> 2;
  int fc = (tid & 3) * 16;
  const float4* hp = reinterpret_cast<const float4*>(h + p * 64 + fc);
  const float4* wp = reinterpret_cast<const float4*>(cw + fc);
  float s = 0.0f;
  #pragma unroll
  for (int i = 0; i < 4; ++i) {
    float4 v = hp[i];
    float4 w = wp[i];
    s += v.x * w.x + v.y * w.y + v.z * w.z + v.w * w.w;
  }
  s += __shfl_xor(s, 1);
  s += __shfl_xor(s, 2);
  if ((tid & 3) == 0) out[p] = s + cbp[0];
}

// ---------------- launch ----------------
extern "C" void kernel_launch(void* const* d_in, const int* in_sizes, int n_in,
                              void* d_out, int out_size, void* d_ws, size_t ws_size,
                              hipStream_t stream) {
  const float* x   = (const float*)d_in[0];
  const float* h0  = (const float*)d_in[1];
  const float* c0  = (const float*)d_in[2];
  const float* h1  = (const float*)d_in[3];
  const float* c1  = (const float*)d_in[4];
  const float* k0  = (const float*)d_in[5];
  const float* rk0 = (const float*)d_in[6];
  const float* b0  = (const float*)d_in[7];
  const float* k1  = (const float*)d_in[8];
  const float* rk1 = (const float*)d_in[9];
  const float* b1  = (const float*)d_in[10];
  const float* cw  = (const float*)d_in[11];
  const float* cbp = (const float*)d_in[12];

  float* out    = (float*)d_out;
  float* frames = out;                       // [32,64,64,1]
  float* h0n    = out + 131072;              // [32,64,64,64]
  float* c0n    = out + 131072 + 8388608;
  float* h1n    = out + 131072 + 2 * 8388608;
  float* c1n    = out + 131072 + 3 * 8388608;

  char* ws = (char*)d_ws;
  const size_t SZ_H = 16777216;  // bytes per bf16 [32,64,64,64] buffer
  s16* h0nb = (s16*)(ws + 0 * SZ_H);
  s16* w0q  = (s16*)(ws + 1 * SZ_H);                 // rk0 shuffled
  s16* w1q  = (s16*)(ws + 1 * SZ_H + 1 * 294912);    // k1 shuffled
  s16* w2q  = (s16*)(ws + 1 * SZ_H + 2 * 294912);    // rk1 shuffled
  s16* k0t  = (s16*)(ws + 1 * SZ_H + 3 * 294912);    // k0 padded [256][32]

  // prep (single launch)
  wprep_kernel<<<1760, 256, 0, stream>>>(rk0, k1, rk1, k0, w0q, w1q, w2q, k0t);

  // layer 0: z = conv(x,k0) + conv(h0,rk0) + b0   (h0 converted inline)
  cell_kernel<1, true, true, false><<<512, 1024, 0, stream>>>(
      h0, nullptr, w0q, nullptr, x, k0t, b0, c0, h0n, c0n, h0nb);

  // layer 1: z = conv(h0n,k1) + conv(h1,rk1) + b1  (h1 converted inline)
  cell_kernel<2, false, false, true><<<512, 1024, 0, stream>>>(
      h0nb, h1, w1q, w2q, nullptr, nullptr, b1, c1, h1n, c1n, nullptr);

  // head
  frames_kernel<<<2048, 256, 0, stream>>>(h1n, cw, cbp, frames);
}